// Round 6
// baseline (310.933 us; speedup 1.0000x reference)
//
#include <hip/hip_runtime.h>
#include <math.h>

#define Bsz 64
#define Tn 1000
#define QD 1024
#define MD 512
#define AD 128
#define NF 32
#define KS 31
#define PADc 15

#define TTB 32  // t-rows per energies block

typedef __attribute__((ext_vector_type(8))) short bf16x8;
typedef __attribute__((ext_vector_type(4))) float f32x4;

#define MEMB_OFF 428032            // byte offset of memB in d_ws
#define MEMB_BYTES 65536000        // 64*1000*512 bf16
#define WS_NEED (MEMB_OFF + MEMB_BYTES)

static __device__ __forceinline__ short f2bf(float x) {
    unsigned u = __float_as_uint(x);
    unsigned r = (u + 0x7fffu + ((u >> 16) & 1u)) >> 16;  // RNE
    return (short)r;
}

static __device__ __forceinline__ float fast_tanh(float x) {
    float e2 = __expf(2.f * x);
    return 1.f - 2.f / (e2 + 1.f);
}

// ---------------------------------------------------------------------------
// Kernel 0: memory (fp32) -> memB (bf16). Pure streaming; the ONLY kernel
// that touches the cold HBM copy of memory. 2048 blocks x 256 thr.
// ---------------------------------------------------------------------------
__global__ __launch_bounds__(256)
void k_convert(const float* __restrict__ mem, short* __restrict__ memB) {
    int g = blockIdx.x * 256 + threadIdx.x;  // 0..524287
#pragma unroll
    for (int u = 0; u < 8; ++u) {
        size_t e = (size_t)(g + u * 524288) * 8;  // element base, 8 floats
        if (e < (size_t)Bsz * Tn * MD) {
            float4 v0 = *(const float4*)(mem + e);
            float4 v1 = *(const float4*)(mem + e + 4);
            bf16x8 o;
            o[0] = f2bf(v0.x); o[1] = f2bf(v0.y); o[2] = f2bf(v0.z); o[3] = f2bf(v0.w);
            o[4] = f2bf(v1.x); o[5] = f2bf(v1.y); o[6] = f2bf(v1.z); o[7] = f2bf(v1.w);
            *(bf16x8*)(memB + e) = o;
        }
    }
}

// ---------------------------------------------------------------------------
// Kernel A (prep, 97 blocks x 256):
//   blocks 0..31  : Wm -> WmF bf16 fragment-major (slot g=(w*16+c)*64+lane)
//   blocks 32..95 : qsum[b][a] = query.Wq + bq + bm + conv_b.Wloc
//   block  96     : W2F fragment-major location-chunk B
// ---------------------------------------------------------------------------
__global__ __launch_bounds__(256)
void k_prep(const float* __restrict__ Wm, const float* __restrict__ conv_w,
            const float* __restrict__ conv_b, const float* __restrict__ Wloc,
            const float* __restrict__ query, const float* __restrict__ Wq,
            const float* __restrict__ bq, const float* __restrict__ bm,
            short* __restrict__ WmF, short* __restrict__ W2F,
            float* __restrict__ qsum) {
    __shared__ float qs[QD];
    __shared__ float red[256];
    int bid = blockIdx.x;
    if (bid < 32) {
        int g = bid * 256 + threadIdx.x;
        int wc = g >> 6, l = g & 63;
        int a = (wc >> 4) * 16 + (l & 15);
        int kb = (wc & 15) * 32 + (l >> 4) * 8;
        const float* src = Wm + a * MD + kb;
        float4 v0 = *(const float4*)src;
        float4 v1 = *(const float4*)(src + 4);
        bf16x8 o;
        o[0] = f2bf(v0.x); o[1] = f2bf(v0.y); o[2] = f2bf(v0.z); o[3] = f2bf(v0.w);
        o[4] = f2bf(v1.x); o[5] = f2bf(v1.y); o[6] = f2bf(v1.z); o[7] = f2bf(v1.w);
        *(bf16x8*)(WmF + (size_t)g * 8) = o;
    } else if (bid < 96) {
        int b = bid - 32;
        int a = threadIdx.x & 127;
        int half = threadIdx.x >> 7;
        for (int i = threadIdx.x; i < QD; i += 256) qs[i] = query[b * QD + i];
        __syncthreads();
        const float4* Wq4 = (const float4*)(Wq + a * QD + half * (QD / 2));
        const float4* qs4 = (const float4*)(qs + half * (QD / 2));
        float acc = 0.f;
#pragma unroll 4
        for (int i = 0; i < QD / 8; ++i) {
            float4 w = Wq4[i];
            float4 q = qs4[i];
            acc += w.x * q.x + w.y * q.y + w.z * q.z + w.w * q.w;
        }
        red[threadIdx.x] = acc;
        __syncthreads();
        if (half == 0) {
            float b2 = 0.f;
            for (int f = 0; f < NF; ++f) b2 += conv_b[f] * Wloc[a * NF + f];
            qsum[b * AD + a] = red[a] + red[a + 128] + bq[a] + bm[a] + b2;
        }
    } else {
        for (int s = threadIdx.x * 2; s < threadIdx.x * 2 + 2; ++s) {
            int w = s >> 6, l = s & 63;
            int a = w * 16 + (l & 15);
            int kb = (l >> 4) * 8;
            bf16x8 o;
#pragma unroll
            for (int j = 0; j < 8; ++j) {
                int k = kb + j;
                float sum = 0.f;
                if (k < KS)
                    for (int f = 0; f < NF; ++f) sum += conv_w[f * KS + k] * Wloc[a * NF + f];
                o[j] = f2bf(sum);
            }
            *(bf16x8*)(W2F + s * 8) = o;
        }
    }
}

// ---------------------------------------------------------------------------
// Kernel B: fused energies via bf16 MFMA.
//   512 thr = 8 waves; tile 32t x 128a; wave w owns a-slice [16w,16w+16).
//   B-frags: 17 coalesced 1KB loads -> registers.  A-panel: 32 rows staged
//   coalesced into XOR-swizzled LDS (exactly 32 KB -> 2 blocks/CU; ered
//   reduction buffer aliased into As). K-loop: ds_read_b128 + MFMA only.
//   USE_BF16: stage from L3-hot memB; else from fp32 mem (ws fallback).
// ---------------------------------------------------------------------------
template <bool USE_BF16>
__global__ __launch_bounds__(512)
void k_energies(const float* __restrict__ mem, const short* __restrict__ memB,
                const float* __restrict__ awc,
                const short* __restrict__ WmF, const short* __restrict__ W2F,
                const float* __restrict__ Wv, const float* __restrict__ bv,
                const float* __restrict__ qsum, float* __restrict__ energies) {
    __shared__ short As[TTB * 64 * 8];  // 32 rows x 64 swizzled 16B units = 32 KB

    int b = blockIdx.y;
    int t0 = blockIdx.x * TTB;
    int tid = threadIdx.x;
    int w = tid >> 6;
    int lane = tid & 63;
    int m16 = lane & 15;
    int q = lane >> 4;

    // ---- B fragments -> registers (coalesced, L2-resident) ----
    bf16x8 bf[17];
    const bf16x8* bp = (const bf16x8*)WmF;
#pragma unroll
    for (int c = 0; c < 16; ++c) bf[c] = bp[(w * 16 + c) * 64 + lane];
    bf[16] = ((const bf16x8*)W2F)[w * 64 + lane];

    // ---- stage A panel, XOR-swizzled: unit(row,col) -> row*64 + (col^(row&7)) ----
#pragma unroll
    for (int u = 0; u < 4; ++u) {
        int g = tid + u * 512;     // 16B-unit slot 0..2047
        int row = g >> 6;
        int col = g & 63;
        int t = t0 + row;
        bf16x8 v = {0, 0, 0, 0, 0, 0, 0, 0};
        if (t < Tn) {
            if (USE_BF16) {
                v = *(const bf16x8*)(memB + (((size_t)b * Tn + t) << 9) + col * 8);
            } else {
                const float* src = mem + ((size_t)b * Tn + t) * MD + col * 8;
                float4 v0 = *(const float4*)src;
                float4 v1 = *(const float4*)(src + 4);
                v[0] = f2bf(v0.x); v[1] = f2bf(v0.y); v[2] = f2bf(v0.z); v[3] = f2bf(v0.w);
                v[4] = f2bf(v1.x); v[5] = f2bf(v1.y); v[6] = f2bf(v1.z); v[7] = f2bf(v1.w);
            }
        }
        *(bf16x8*)&As[((row << 6) | (col ^ (row & 7))) * 8] = v;
    }
    __syncthreads();

    // ---- K-loop: LDS a-frags x register b-frags ----
    f32x4 acc0 = {0.f, 0.f, 0.f, 0.f}, acc1 = acc0;
    int x0 = m16 & 7, r1 = 16 + m16;
#pragma unroll
    for (int c = 0; c < 16; ++c) {
        int u = c * 4 + q;
        bf16x8 a0 = *(const bf16x8*)&As[((m16 << 6) | (u ^ x0)) * 8];
        bf16x8 a1 = *(const bf16x8*)&As[((r1 << 6) | (u ^ x0)) * 8];
        acc0 = __builtin_amdgcn_mfma_f32_16x16x32_bf16(a0, bf[c], acc0, 0, 0, 0);
        acc1 = __builtin_amdgcn_mfma_f32_16x16x32_bf16(a1, bf[c], acc1, 0, 0, 0);
    }
    {   // location chunk: Toeplitz of awc (small, cache-hot gathers)
        bf16x8 a0, a1;
        int tA = t0 + m16, tB = tA + 16;
#pragma unroll
        for (int j = 0; j < 8; ++j) {
            int kk = q * 8 + j;
            int s0 = tA + kk - PADc, s1 = tB + kk - PADc;
            float v0 = (kk < KS && s0 >= 0 && s0 < Tn) ? awc[b * Tn + s0] : 0.f;
            float v1 = (kk < KS && s1 >= 0 && s1 < Tn) ? awc[b * Tn + s1] : 0.f;
            a0[j] = f2bf(v0);
            a1[j] = f2bf(v1);
        }
        acc0 = __builtin_amdgcn_mfma_f32_16x16x32_bf16(a0, bf[16], acc0, 0, 0, 0);
        acc1 = __builtin_amdgcn_mfma_f32_16x16x32_bf16(a1, bf[16], acc1, 0, 0, 0);
    }

    // ---- epilogue: tanh, dot Wv, wave-reduce, cross-wave via aliased LDS ----
    __syncthreads();               // all As reads done; reuse As as ered
    float* ered = (float*)As;      // [8][33]
    int a = w * 16 + m16;
    float wvv = Wv[a];
    float qsv = qsum[b * AD + a];
#pragma unroll
    for (int r = 0; r < 4; ++r) {
        float e0 = wvv * fast_tanh(acc0[r] + qsv);
        float e1 = wvv * fast_tanh(acc1[r] + qsv);
#pragma unroll
        for (int m2 = 1; m2 < 16; m2 <<= 1) {
            e0 += __shfl_xor(e0, m2, 64);
            e1 += __shfl_xor(e1, m2, 64);
        }
        if (m16 == 0) {
            ered[w * 33 + q * 4 + r] = e0;
            ered[w * 33 + 16 + q * 4 + r] = e1;
        }
    }
    __syncthreads();
    if (tid < TTB) {
        float E = bv[0];
#pragma unroll
        for (int ww = 0; ww < 8; ++ww) E += ered[ww * 33 + tid];
        int t = t0 + tid;
        if (t < Tn) energies[b * Tn + t] = E;
    }
}

// ---------------------------------------------------------------------------
// Kernel C: masked softmax over T per batch row; also zero-inits ctx[b].
// ---------------------------------------------------------------------------
__global__ __launch_bounds__(256)
void k_softmax(const float* __restrict__ energies, const unsigned char* __restrict__ mask,
               float* __restrict__ wout, float* __restrict__ ctx) {
    int b = blockIdx.x;
    int tid = threadIdx.x;
    __shared__ float red[256];

    ctx[b * MD + tid] = 0.f;
    ctx[b * MD + 256 + tid] = 0.f;

    float e[4];
    float lmax = -1e30f;
#pragma unroll
    for (int i = 0; i < 4; ++i) {
        int t = tid + i * 256;
        float v = -1e30f;
        if (t < Tn) {
            v = energies[b * Tn + t];
            if (mask[b * Tn + t]) v = -1e30f;
        }
        e[i] = v;
        lmax = fmaxf(lmax, v);
    }
    red[tid] = lmax;
    __syncthreads();
    for (int s = 128; s > 0; s >>= 1) {
        if (tid < s) red[tid] = fmaxf(red[tid], red[tid + s]);
        __syncthreads();
    }
    float smax = red[0];
    __syncthreads();

    float ex[4];
    float lsum = 0.f;
#pragma unroll
    for (int i = 0; i < 4; ++i) {
        ex[i] = __expf(e[i] - smax);
        lsum += ex[i];
    }
    red[tid] = lsum;
    __syncthreads();
    for (int s = 128; s > 0; s >>= 1) {
        if (tid < s) red[tid] += red[tid + s];
        __syncthreads();
    }
    float inv = 1.f / red[0];
#pragma unroll
    for (int i = 0; i < 4; ++i) {
        int t = tid + i * 256;
        if (t < Tn) wout[b * Tn + t] = ex[i] * inv;
    }
}

// ---------------------------------------------------------------------------
// Kernel D: context[b,m] = sum_t w[b,t]*memory[b,t,m]  (fp32 memory, L3-hot)
// ---------------------------------------------------------------------------
__global__ __launch_bounds__(256)
void k_context(const float* __restrict__ mem, const float* __restrict__ w,
               float* __restrict__ ctx) {
    int tc = blockIdx.x;
    int b = blockIdx.y;
    int tid = threadIdx.x;
    __shared__ float ws[64];
    int tstart = tc * 64;
    if (tid < 64) {
        int tt = tstart + tid;
        ws[tid] = (tt < Tn) ? w[b * Tn + tt] : 0.f;
    }
    __syncthreads();
    const float* mb = mem + (size_t)b * Tn * MD + tid * 2;
    float a0 = 0.f, a1 = 0.f;
    int nrow = (tstart + 64 <= Tn) ? 64 : (Tn - tstart);
    for (int i = 0; i < nrow; ++i) {
        float wv = ws[i];
        float2 v = *(const float2*)(mb + (size_t)(tstart + i) * MD);
        a0 += wv * v.x;
        a1 += wv * v.y;
    }
    atomicAdd(&ctx[b * MD + tid * 2], a0);
    atomicAdd(&ctx[b * MD + tid * 2 + 1], a1);
}

// ---------------------------------------------------------------------------
extern "C" void kernel_launch(void* const* d_in, const int* in_sizes, int n_in,
                              void* d_out, int out_size, void* d_ws, size_t ws_size,
                              hipStream_t stream) {
    const float* query  = (const float*)d_in[0];
    const float* memory = (const float*)d_in[1];
    const float* awc    = (const float*)d_in[2];
    const unsigned char* mask = (const unsigned char*)d_in[3];
    const float* Wq     = (const float*)d_in[4];
    const float* bq     = (const float*)d_in[5];
    const float* Wm     = (const float*)d_in[6];
    const float* bm     = (const float*)d_in[7];
    const float* Wv     = (const float*)d_in[8];
    const float* bv     = (const float*)d_in[9];
    const float* conv_w = (const float*)d_in[10];
    const float* conv_b = (const float*)d_in[11];
    const float* Wloc   = (const float*)d_in[12];

    float* out = (float*)d_out;
    float* ctx = out;             // [64,512]
    float* wout = out + Bsz * MD; // [64,1000]

    float* ws = (float*)d_ws;
    float* qsum  = ws;             // 8192 f
    float* energ = ws + 8192;      // 64000 f -> ends at byte 288768
    short* WmF = (short*)((char*)d_ws + 288768);           // 128 KB
    short* W2F = (short*)((char*)d_ws + 288768 + 131072);  // 8 KB
    short* memB = (short*)((char*)d_ws + MEMB_OFF);        // 65.5 MB bf16

    bool use_bf16 = (ws_size >= (size_t)WS_NEED);

    k_prep<<<dim3(97), dim3(256), 0, stream>>>(Wm, conv_w, conv_b, Wloc, query, Wq,
                                               bq, bm, WmF, W2F, qsum);
    if (use_bf16) {
        k_convert<<<dim3(2048), dim3(256), 0, stream>>>(memory, memB);
        k_energies<true><<<dim3((Tn + TTB - 1) / TTB, Bsz), dim3(512), 0, stream>>>(
            memory, memB, awc, WmF, W2F, Wv, bv, qsum, energ);
    } else {
        k_energies<false><<<dim3((Tn + TTB - 1) / TTB, Bsz), dim3(512), 0, stream>>>(
            memory, memB, awc, WmF, W2F, Wv, bv, qsum, energ);
    }
    k_softmax<<<dim3(Bsz), dim3(256), 0, stream>>>(energ, mask, wout, ctx);
    k_context<<<dim3(16, Bsz), dim3(256), 0, stream>>>(memory, wout, ctx);
}

// Round 7
// 309.177 us; speedup vs baseline: 1.0057x; 1.0057x over previous
//
#include <hip/hip_runtime.h>
#include <math.h>

#define Bsz 64
#define Tn 1000
#define QD 1024
#define MD 512
#define AD 128
#define NF 32
#define KS 31
#define PADc 15

#define NCH 16   // t-chunks
#define RPC 64   // rows per chunk
#define SUB 16   // rows per subtile

typedef __attribute__((ext_vector_type(8))) short bf16x8;
typedef __attribute__((ext_vector_type(4))) float f32x4;

static __device__ __forceinline__ short f2bf(float x) {
    unsigned u = __float_as_uint(x);
    unsigned r = (u + 0x7fffu + ((u >> 16) & 1u)) >> 16;  // RNE
    return (short)r;
}
static __device__ __forceinline__ float bf2f(short s) {
    return __uint_as_float(((unsigned)(unsigned short)s) << 16);
}
static __device__ __forceinline__ float fast_tanh(float x) {
    float e2 = __expf(2.f * x);
    return 1.f - 2.f / (e2 + 1.f);
}

// ---------------------------------------------------------------------------
// Kernel A (prep, 97 blocks x 256):
//   blocks 0..31  : Wm -> WmF bf16 fragment-major (slot g=(w*16+c)*64+lane)
//   blocks 32..95 : qsum[b][a] = query.Wq + bq + bm + conv_b.Wloc
//   block  96     : W2F fragment-major location-chunk B
// ---------------------------------------------------------------------------
__global__ __launch_bounds__(256)
void k_prep(const float* __restrict__ Wm, const float* __restrict__ conv_w,
            const float* __restrict__ conv_b, const float* __restrict__ Wloc,
            const float* __restrict__ query, const float* __restrict__ Wq,
            const float* __restrict__ bq, const float* __restrict__ bm,
            short* __restrict__ WmF, short* __restrict__ W2F,
            float* __restrict__ qsum) {
    __shared__ float qs[QD];
    __shared__ float red[256];
    int bid = blockIdx.x;
    if (bid < 32) {
        int g = bid * 256 + threadIdx.x;
        int wc = g >> 6, l = g & 63;
        int a = (wc >> 4) * 16 + (l & 15);
        int kb = (wc & 15) * 32 + (l >> 4) * 8;
        const float* src = Wm + a * MD + kb;
        float4 v0 = *(const float4*)src;
        float4 v1 = *(const float4*)(src + 4);
        bf16x8 o;
        o[0] = f2bf(v0.x); o[1] = f2bf(v0.y); o[2] = f2bf(v0.z); o[3] = f2bf(v0.w);
        o[4] = f2bf(v1.x); o[5] = f2bf(v1.y); o[6] = f2bf(v1.z); o[7] = f2bf(v1.w);
        *(bf16x8*)(WmF + (size_t)g * 8) = o;
    } else if (bid < 96) {
        int b = bid - 32;
        int a = threadIdx.x & 127;
        int half = threadIdx.x >> 7;
        for (int i = threadIdx.x; i < QD; i += 256) qs[i] = query[b * QD + i];
        __syncthreads();
        const float4* Wq4 = (const float4*)(Wq + a * QD + half * (QD / 2));
        const float4* qs4 = (const float4*)(qs + half * (QD / 2));
        float acc = 0.f;
#pragma unroll 4
        for (int i = 0; i < QD / 8; ++i) {
            float4 w = Wq4[i];
            float4 q = qs4[i];
            acc += w.x * q.x + w.y * q.y + w.z * q.z + w.w * q.w;
        }
        red[threadIdx.x] = acc;
        __syncthreads();
        if (half == 0) {
            float b2 = 0.f;
            for (int f = 0; f < NF; ++f) b2 += conv_b[f] * Wloc[a * NF + f];
            qsum[b * AD + a] = red[a] + red[a + 128] + bq[a] + bm[a] + b2;
        }
    } else {
        for (int s = threadIdx.x * 2; s < threadIdx.x * 2 + 2; ++s) {
            int w = s >> 6, l = s & 63;
            int a = w * 16 + (l & 15);
            int kb = (l >> 4) * 8;
            bf16x8 o;
#pragma unroll
            for (int j = 0; j < 8; ++j) {
                int k = kb + j;
                float sum = 0.f;
                if (k < KS)
                    for (int f = 0; f < NF; ++f) sum += conv_w[f * KS + k] * Wloc[a * NF + f];
                o[j] = f2bf(sum);
            }
            *(bf16x8*)(W2F + s * 8) = o;
        }
    }
}

// ---------------------------------------------------------------------------
// Kernel B: FULLY FUSED energies -> online softmax -> context partials.
//   Grid (16 chunks, 64 b), 512 thr = 8 waves. Each block streams 64 t-rows
//   of memory[b] in 4 subtiles of 16 rows (bf16, XOR-swizzled LDS, double-
//   buffered; loads for s+1 issued before compute(s), LDS writes after).
//   Energies: wave w owns a-slice [16w,16w+16), 17 MFMA chunks (16 key +
//   Toeplitz loc). Online softmax per block; ctx: thread j accumulates
//   m-dim j from the LDS tile. Emits (m,l) + ctx[512] partials + raw energies.
// ---------------------------------------------------------------------------
__global__ __launch_bounds__(512)
void k_fused(const float* __restrict__ mem, const float* __restrict__ awc,
             const unsigned char* __restrict__ mask,
             const short* __restrict__ WmF, const short* __restrict__ W2F,
             const float* __restrict__ Wv, const float* __restrict__ bv,
             const float* __restrict__ qsum, float* __restrict__ energ,
             float* __restrict__ ctxc, float2* __restrict__ ml) {
    __shared__ short As[2][SUB * 64 * 8];  // 2 x 16 KB bf16 tiles
    __shared__ float ered[8][SUB + 1];
    __shared__ float es[SUB], ps[SUB];

    int b = blockIdx.y;
    int c = blockIdx.x;
    int t0 = c * RPC;
    int tid = threadIdx.x;
    int w = tid >> 6;
    int lane = tid & 63;
    int m16 = lane & 15;
    int q = lane >> 4;

    // ---- persistent B fragments (17 x 16B coalesced, L2-resident) ----
    bf16x8 bf[17];
    const bf16x8* bp = (const bf16x8*)WmF;
#pragma unroll
    for (int cc = 0; cc < 16; ++cc) bf[cc] = bp[(w * 16 + cc) * 64 + lane];
    bf[16] = ((const bf16x8*)W2F)[w * 64 + lane];

    int a = w * 16 + m16;
    float wvv = Wv[a];
    float qsv = qsum[b * AD + a];
    float bv0 = bv[0];

    float ctxj = 0.f;          // thread j = tid accumulates m-dim tid
    float m_run = -1e30f, l_run = 0.f;

    float4 vreg[4];            // staged fp32 for the in-flight subtile

    auto load_sub = [&](int s) {
#pragma unroll
        for (int i = 0; i < 2; ++i) {
            int g = tid + i * 512;           // 16B-unit slot 0..1023
            int row = g >> 6;
            int col = g & 63;
            int t = t0 + s * SUB + row;
            if (t < Tn) {
                const float* src = mem + ((size_t)b * Tn + t) * MD + col * 8;
                vreg[i * 2] = *(const float4*)src;
                vreg[i * 2 + 1] = *(const float4*)(src + 4);
            } else {
                vreg[i * 2] = make_float4(0.f, 0.f, 0.f, 0.f);
                vreg[i * 2 + 1] = vreg[i * 2];
            }
        }
    };
    auto write_sub = [&](int buf) {
#pragma unroll
        for (int i = 0; i < 2; ++i) {
            int g = tid + i * 512;
            int row = g >> 6;
            int col = g & 63;
            float4 v0 = vreg[i * 2], v1 = vreg[i * 2 + 1];
            bf16x8 o;
            o[0] = f2bf(v0.x); o[1] = f2bf(v0.y); o[2] = f2bf(v0.z); o[3] = f2bf(v0.w);
            o[4] = f2bf(v1.x); o[5] = f2bf(v1.y); o[6] = f2bf(v1.z); o[7] = f2bf(v1.w);
            *(bf16x8*)&As[buf][((row << 6) | (col ^ (row & 7))) * 8] = o;
        }
    };

    load_sub(0);
    write_sub(0);

    for (int s = 0; s < 4; ++s) {
        __syncthreads();                     // tile s visible; prev readers done
        if (s < 3) load_sub(s + 1);          // fire next loads (no waits yet)

        int buf = s & 1;
        const short* tile = As[buf];

        // ---- energies MFMA: 16 key chunks + loc chunk ----
        f32x4 acc = {0.f, 0.f, 0.f, 0.f};
        int x0 = m16 & 7;
#pragma unroll
        for (int cc = 0; cc < 16; ++cc) {
            int u = cc * 4 + q;
            bf16x8 af = *(const bf16x8*)&tile[((m16 << 6) | (u ^ x0)) * 8];
            acc = __builtin_amdgcn_mfma_f32_16x16x32_bf16(af, bf[cc], acc, 0, 0, 0);
        }
        {
            int trow = t0 + s * SUB + m16;
            bf16x8 af;
#pragma unroll
            for (int j = 0; j < 8; ++j) {
                int kk = q * 8 + j;
                int ts = trow + kk - PADc;
                float v = (kk < KS && ts >= 0 && ts < Tn) ? awc[b * Tn + ts] : 0.f;
                af[j] = f2bf(v);
            }
            acc = __builtin_amdgcn_mfma_f32_16x16x32_bf16(af, bf[16], acc, 0, 0, 0);
        }

        // ---- per-row energy partials: tanh, dot Wv, reduce over 16 a-lanes ----
#pragma unroll
        for (int r = 0; r < 4; ++r) {
            float e = wvv * fast_tanh(acc[r] + qsv);
#pragma unroll
            for (int m2 = 1; m2 < 16; m2 <<= 1) e += __shfl_xor(e, m2, 64);
            if (m16 == 0) ered[w][q * 4 + r] = e;
        }
        __syncthreads();
        if (tid < SUB) {
            float E = bv0;
#pragma unroll
            for (int ww = 0; ww < 8; ++ww) E += ered[ww][tid];
            int t = t0 + s * SUB + tid;
            bool valid = (t < Tn);
            bool msk = valid ? (mask[b * Tn + t] != 0) : true;
            if (valid) energ[b * Tn + t] = E;   // raw energy for wout pass
            es[tid] = (valid && !msk) ? E : -1e30f;
        }
        __syncthreads();

        // ---- online softmax update (block-uniform scalars) ----
        float mx = m_run;
#pragma unroll
        for (int r = 0; r < SUB; ++r) mx = fmaxf(mx, es[r]);
        if (tid < SUB) ps[tid] = (es[tid] <= -1e29f) ? 0.f : __expf(es[tid] - mx);
        __syncthreads();
        float alpha = __expf(m_run - mx);
        float psum = 0.f, cacc = 0.f;
#pragma unroll
        for (int r = 0; r < SUB; ++r) {
            float p = ps[r];
            psum += p;
            short sv = tile[((r << 6) | ((tid >> 3) ^ (r & 7))) * 8 + (tid & 7)];
            cacc += p * bf2f(sv);
        }
        ctxj = ctxj * alpha + cacc;
        l_run = l_run * alpha + psum;
        m_run = mx;

        if (s < 3) write_sub((s + 1) & 1);   // vmcnt waits land after compute
    }

    // ---- emit chunk partials ----
    ctxc[((size_t)c * Bsz + b) * MD + tid] = ctxj;
    if (tid == 0) ml[c * Bsz + b] = make_float2(m_run, l_run);
}

// ---------------------------------------------------------------------------
// Kernel C: combine partials -> ctx, and raw energies -> wout.
// ---------------------------------------------------------------------------
__global__ __launch_bounds__(512)
void k_combine(const float* __restrict__ ctxc, const float2* __restrict__ ml,
               const float* __restrict__ energ, const unsigned char* __restrict__ mask,
               float* __restrict__ ctx, float* __restrict__ wout) {
    __shared__ float sm[NCH], sl[NCH];
    int b = blockIdx.x;
    int tid = threadIdx.x;
    if (tid < NCH) {
        float2 v = ml[tid * Bsz + b];
        sm[tid] = v.x;
        sl[tid] = v.y;
    }
    __syncthreads();
    float M = -1e30f;
#pragma unroll
    for (int cc = 0; cc < NCH; ++cc) M = fmaxf(M, sm[cc]);
    float L = 0.f;
#pragma unroll
    for (int cc = 0; cc < NCH; ++cc) L += sl[cc] * __expf(sm[cc] - M);
    float inv = 1.f / L;

    float s = 0.f;
#pragma unroll
    for (int cc = 0; cc < NCH; ++cc)
        s += ctxc[((size_t)cc * Bsz + b) * MD + tid] * __expf(sm[cc] - M);
    ctx[b * MD + tid] = s * inv;

#pragma unroll
    for (int i = 0; i < 2; ++i) {
        int t = tid + i * 512;
        if (t < Tn) {
            bool msk = mask[b * Tn + t] != 0;
            float e = energ[b * Tn + t];
            wout[b * Tn + t] = msk ? 0.f : __expf(e - M) * inv;
        }
    }
}

// ---------------------------------------------------------------------------
extern "C" void kernel_launch(void* const* d_in, const int* in_sizes, int n_in,
                              void* d_out, int out_size, void* d_ws, size_t ws_size,
                              hipStream_t stream) {
    const float* query  = (const float*)d_in[0];
    const float* memory = (const float*)d_in[1];
    const float* awc    = (const float*)d_in[2];
    const unsigned char* mask = (const unsigned char*)d_in[3];
    const float* Wq     = (const float*)d_in[4];
    const float* bq     = (const float*)d_in[5];
    const float* Wm     = (const float*)d_in[6];
    const float* bm     = (const float*)d_in[7];
    const float* Wv     = (const float*)d_in[8];
    const float* bv     = (const float*)d_in[9];
    const float* conv_w = (const float*)d_in[10];
    const float* conv_b = (const float*)d_in[11];
    const float* Wloc   = (const float*)d_in[12];

    float* out = (float*)d_out;
    float* ctx = out;             // [64,512]
    float* wout = out + Bsz * MD; // [64,1000]

    float* qsum  = (float*)d_ws;                            // 8192 f
    float* energ = (float*)d_ws + 8192;                     // 64000 f -> byte 288768
    short* WmF = (short*)((char*)d_ws + 288768);            // 128 KB
    short* W2F = (short*)((char*)d_ws + 288768 + 131072);   // 8 KB -> byte 428032
    float2* ml = (float2*)((char*)d_ws + 428032);           // 16*64*8 B = 8 KB
    float* ctxc = (float*)((char*)d_ws + 436224);           // 16*64*512*4 = 2 MB

    k_prep<<<dim3(97), dim3(256), 0, stream>>>(Wm, conv_w, conv_b, Wloc, query, Wq,
                                               bq, bm, WmF, W2F, qsum);
    k_fused<<<dim3(NCH, Bsz), dim3(512), 0, stream>>>(
        memory, awc, mask, WmF, W2F, Wv, bv, qsum, energ, ctxc, ml);
    k_combine<<<dim3(Bsz), dim3(512), 0, stream>>>(ctxc, ml, energ, mask, ctx, wout);
}

// Round 8
// 279.627 us; speedup vs baseline: 1.1120x; 1.1057x over previous
//
#include <hip/hip_runtime.h>
#include <math.h>

#define Bsz 64
#define Tn 1000
#define QD 1024
#define MD 512
#define AD 128
#define NF 32
#define KS 31
#define PADc 15

#define NCH 16     // t-chunks
#define RPC 64     // rows per chunk
#define SUB 16     // rows per MFMA subtile
#define ROWSH 520  // shorts per LDS row (512 data + 8 pad) = 1040 B

typedef __attribute__((ext_vector_type(8))) short bf16x8;
typedef __attribute__((ext_vector_type(4))) float f32x4;

// d_ws layout (bytes)
#define OFF_ENERG 32768
#define OFF_WMF  288768
#define OFF_W2F  419840
#define OFF_ML   428032
#define OFF_CTXC 436224
#define OFF_MEMB 2533376   // 16-aligned; memB = 64*1000*512 bf16 = 65.5 MB

static __device__ __forceinline__ short f2bf(float x) {
    unsigned u = __float_as_uint(x);
    unsigned r = (u + 0x7fffu + ((u >> 16) & 1u)) >> 16;  // RNE
    return (short)r;
}
static __device__ __forceinline__ float bf2f(short s) {
    return __uint_as_float(((unsigned)(unsigned short)s) << 16);
}
static __device__ __forceinline__ float fast_tanh(float x) {
    float e2 = __expf(2.f * x);
    return 1.f - 2.f / (e2 + 1.f);
}

// ---------------------------------------------------------------------------
// Kernel 0: memory (fp32) -> memB (bf16). Pure streaming first touch.
// ---------------------------------------------------------------------------
__global__ __launch_bounds__(256)
void k_convert(const float* __restrict__ mem, short* __restrict__ memB) {
    int g = blockIdx.x * 256 + threadIdx.x;  // 0..524287
#pragma unroll
    for (int u = 0; u < 8; ++u) {
        size_t e = (size_t)(g + u * 524288) * 8;
        if (e < (size_t)Bsz * Tn * MD) {
            float4 v0 = *(const float4*)(mem + e);
            float4 v1 = *(const float4*)(mem + e + 4);
            bf16x8 o;
            o[0] = f2bf(v0.x); o[1] = f2bf(v0.y); o[2] = f2bf(v0.z); o[3] = f2bf(v0.w);
            o[4] = f2bf(v1.x); o[5] = f2bf(v1.y); o[6] = f2bf(v1.z); o[7] = f2bf(v1.w);
            *(bf16x8*)(memB + e) = o;
        }
    }
}

// ---------------------------------------------------------------------------
// Kernel A (prep, 97 blocks x 256): WmF fragment-major bf16; qsum; W2F.
// ---------------------------------------------------------------------------
__global__ __launch_bounds__(256)
void k_prep(const float* __restrict__ Wm, const float* __restrict__ conv_w,
            const float* __restrict__ conv_b, const float* __restrict__ Wloc,
            const float* __restrict__ query, const float* __restrict__ Wq,
            const float* __restrict__ bq, const float* __restrict__ bm,
            short* __restrict__ WmF, short* __restrict__ W2F,
            float* __restrict__ qsum) {
    __shared__ float qs[QD];
    __shared__ float red[256];
    int bid = blockIdx.x;
    if (bid < 32) {
        int g = bid * 256 + threadIdx.x;
        int wc = g >> 6, l = g & 63;
        int a = (wc >> 4) * 16 + (l & 15);
        int kb = (wc & 15) * 32 + (l >> 4) * 8;
        const float* src = Wm + a * MD + kb;
        float4 v0 = *(const float4*)src;
        float4 v1 = *(const float4*)(src + 4);
        bf16x8 o;
        o[0] = f2bf(v0.x); o[1] = f2bf(v0.y); o[2] = f2bf(v0.z); o[3] = f2bf(v0.w);
        o[4] = f2bf(v1.x); o[5] = f2bf(v1.y); o[6] = f2bf(v1.z); o[7] = f2bf(v1.w);
        *(bf16x8*)(WmF + (size_t)g * 8) = o;
    } else if (bid < 96) {
        int b = bid - 32;
        int a = threadIdx.x & 127;
        int half = threadIdx.x >> 7;
        for (int i = threadIdx.x; i < QD; i += 256) qs[i] = query[b * QD + i];
        __syncthreads();
        const float4* Wq4 = (const float4*)(Wq + a * QD + half * (QD / 2));
        const float4* qs4 = (const float4*)(qs + half * (QD / 2));
        float acc = 0.f;
#pragma unroll 4
        for (int i = 0; i < QD / 8; ++i) {
            float4 w = Wq4[i];
            float4 q = qs4[i];
            acc += w.x * q.x + w.y * q.y + w.z * q.z + w.w * q.w;
        }
        red[threadIdx.x] = acc;
        __syncthreads();
        if (half == 0) {
            float b2 = 0.f;
            for (int f = 0; f < NF; ++f) b2 += conv_b[f] * Wloc[a * NF + f];
            qsum[b * AD + a] = red[a] + red[a + 128] + bq[a] + bm[a] + b2;
        }
    } else {
        for (int s = threadIdx.x * 2; s < threadIdx.x * 2 + 2; ++s) {
            int w = s >> 6, l = s & 63;
            int a = w * 16 + (l & 15);
            int kb = (l >> 4) * 8;
            bf16x8 o;
#pragma unroll
            for (int j = 0; j < 8; ++j) {
                int k = kb + j;
                float sum = 0.f;
                if (k < KS)
                    for (int f = 0; f < NF; ++f) sum += conv_w[f * KS + k] * Wloc[a * NF + f];
                o[j] = f2bf(sum);  // k>=KS columns are ZERO -> no A-side guard needed
            }
            *(bf16x8*)(W2F + s * 8) = o;
        }
    }
}

// ---------------------------------------------------------------------------
// Kernel B: fused energies + softmax + context, async-DMA edition.
//   512 thr = 8 waves; block owns 64 t-rows, ALL staged via
//   global_load_lds (async, lane-linear, 1040B-padded rows) into one 66.5 KB
//   LDS chunk. All 8 DMA transfers per wave issued up-front; per subtile only
//   s_waitcnt vmcnt(N) + raw s_barrier. Zero in-loop VMEM (awc window + mask
//   pre-staged in LDS). After 4 MFMA subtiles: one block-wide softmax and a
//   ctx pass over the resident LDS chunk. Emits (m,l), ctx partials, raw E.
// ---------------------------------------------------------------------------
__global__ __launch_bounds__(512)
void k_fused(const short* __restrict__ memB, const float* __restrict__ awc,
             const unsigned char* __restrict__ mask,
             const short* __restrict__ WmF, const short* __restrict__ W2F,
             const float* __restrict__ Wv, const float* __restrict__ bv,
             const float* __restrict__ qsum, float* __restrict__ energ,
             float* __restrict__ ctxc, float2* __restrict__ ml) {
    __shared__ __align__(16) short chunk[RPC * ROWSH];  // 66560 B
    __shared__ float ered[8][SUB + 1];
    __shared__ float Esub[RPC];
    __shared__ float ps[RPC];
    __shared__ float vmask[RPC];
    __shared__ short awcsB[96];

    const int b = blockIdx.y, c = blockIdx.x;
    const int t0 = c * RPC;
    const int tid = threadIdx.x;
    const int w = tid >> 6, lane = tid & 63, m16 = lane & 15, q = lane >> 4;

    // --- B fragments first (their waits must precede the DMA queue) ---
    bf16x8 bf[17];
#pragma unroll
    for (int cc = 0; cc < 16; ++cc) bf[cc] = ((const bf16x8*)WmF)[(w * 16 + cc) * 64 + lane];
    bf[16] = ((const bf16x8*)W2F)[w * 64 + lane];

    const int a = w * 16 + m16;
    const float wvv = Wv[a];
    const float qsv = qsum[b * AD + a];
    const float bv0 = bv[0];

    // --- stage awc window [t0-15, t0+79] and row-validity into LDS ---
    if (tid < 96) {
        int g = t0 - PADc + tid;
        float v = (tid <= 94 && g >= 0 && g < Tn) ? awc[b * Tn + g] : 0.f;
        awcsB[tid] = f2bf(v);
    }
    if (tid < RPC) {
        int t = t0 + tid;
        bool valid = (t < Tn) && (mask[b * Tn + (t < Tn ? t : 0)] == 0);
        vmask[tid] = valid ? 1.f : 0.f;
    }

    // --- issue ALL DMA transfers: wave w -> rows s*16+2w, s*16+2w+1 ---
#pragma unroll
    for (int s = 0; s < 4; ++s) {
#pragma unroll
        for (int rr = 0; rr < 2; ++rr) {
            int row = s * SUB + w * 2 + rr;
            int t = t0 + row;
            int tc = t < Tn ? t : Tn - 1;
            const short* gp = memB + (((size_t)b * Tn + tc) << 9) + lane * 8;
            short* lp = &chunk[row * ROWSH] + lane * 8;
            __builtin_amdgcn_global_load_lds(
                (const __attribute__((address_space(1))) void*)gp,
                (__attribute__((address_space(3))) void*)lp, 16, 0, 0);
        }
    }

    asm volatile("s_waitcnt lgkmcnt(0)" ::: "memory");
    __builtin_amdgcn_s_barrier();  // awcsB / vmask visible

#pragma unroll
    for (int s = 0; s < 4; ++s) {
        // wait own subtile-s DMAs (2*(3-s) younger remain), then rendezvous
        switch (s) {
            case 0: asm volatile("s_waitcnt vmcnt(6)" ::: "memory"); break;
            case 1: asm volatile("s_waitcnt vmcnt(4)" ::: "memory"); break;
            case 2: asm volatile("s_waitcnt vmcnt(2)" ::: "memory"); break;
            default: asm volatile("s_waitcnt vmcnt(0)" ::: "memory"); break;
        }
        __builtin_amdgcn_s_barrier();

        f32x4 acc = (f32x4){0.f, 0.f, 0.f, 0.f};
        const short* arow = &chunk[(s * SUB + m16) * ROWSH + q * 8];
#pragma unroll
        for (int cc = 0; cc < 16; ++cc) {
            bf16x8 af = *(const bf16x8*)(arow + cc * 32);
            acc = __builtin_amdgcn_mfma_f32_16x16x32_bf16(af, bf[cc], acc, 0, 0, 0);
        }
        {   // location chunk: Toeplitz window from LDS (k=31 col zeroed in W2F)
            int tl = s * SUB + m16;
            bf16x8 af;
#pragma unroll
            for (int j = 0; j < 8; ++j) af[j] = awcsB[tl + q * 8 + j];
            acc = __builtin_amdgcn_mfma_f32_16x16x32_bf16(af, bf[16], acc, 0, 0, 0);
        }

        // per-row energy partials: tanh, dot Wv, reduce over 16 a-lanes
#pragma unroll
        for (int r = 0; r < 4; ++r) {
            float e = wvv * fast_tanh(acc[r] + qsv);
#pragma unroll
            for (int m2 = 1; m2 < 16; m2 <<= 1) e += __shfl_xor(e, m2, 64);
            if (m16 == 0) ered[w][q * 4 + r] = e;
        }
        asm volatile("s_waitcnt lgkmcnt(0)" ::: "memory");
        __builtin_amdgcn_s_barrier();
        if (tid < SUB) {
            float E = bv0;
#pragma unroll
            for (int ww = 0; ww < 8; ++ww) E += ered[ww][tid];
            Esub[s * SUB + tid] = E;
        }
        // ered reuse in s+1 is safe: next write happens after s+1's top barrier
    }

    asm volatile("s_waitcnt lgkmcnt(0)" ::: "memory");
    __builtin_amdgcn_s_barrier();  // Esub complete

    // --- block softmax over the 64 resident rows ---
    float mx = -1e30f;
#pragma unroll
    for (int r = 0; r < RPC; ++r) {
        float e = (vmask[r] != 0.f) ? Esub[r] : -1e30f;
        mx = fmaxf(mx, e);
    }
    if (tid < RPC) ps[tid] = vmask[tid] * __expf(Esub[tid] - mx);
    asm volatile("s_waitcnt lgkmcnt(0)" ::: "memory");
    __builtin_amdgcn_s_barrier();

    // --- context: thread j accumulates m-dim j from the LDS chunk ---
    float ctxj = 0.f, psum = 0.f;
#pragma unroll 8
    for (int r = 0; r < RPC; ++r) {
        float p = ps[r];
        psum += p;
        ctxj += p * bf2f(chunk[r * ROWSH + tid]);
    }
    ctxc[((size_t)c * Bsz + b) * MD + tid] = ctxj;
    if (tid < RPC) {
        int t = t0 + tid;
        if (t < Tn) energ[b * Tn + t] = Esub[tid];
    }
    if (tid == 0) ml[c * Bsz + b] = make_float2(mx, psum);
}

// ---------------------------------------------------------------------------
// Kernel C: combine partials -> ctx, and raw energies -> wout.
// ---------------------------------------------------------------------------
__global__ __launch_bounds__(512)
void k_combine(const float* __restrict__ ctxc, const float2* __restrict__ ml,
               const float* __restrict__ energ, const unsigned char* __restrict__ mask,
               float* __restrict__ ctx, float* __restrict__ wout) {
    __shared__ float sm[NCH], sl[NCH];
    int b = blockIdx.x;
    int tid = threadIdx.x;
    if (tid < NCH) {
        float2 v = ml[tid * Bsz + b];
        sm[tid] = v.x;
        sl[tid] = v.y;
    }
    __syncthreads();
    float M = -1e30f;
#pragma unroll
    for (int cc = 0; cc < NCH; ++cc) M = fmaxf(M, sm[cc]);
    float L = 0.f;
#pragma unroll
    for (int cc = 0; cc < NCH; ++cc) L += sl[cc] * __expf(sm[cc] - M);
    float inv = 1.f / L;

    float s = 0.f;
#pragma unroll
    for (int cc = 0; cc < NCH; ++cc)
        s += ctxc[((size_t)cc * Bsz + b) * MD + tid] * __expf(sm[cc] - M);
    ctx[b * MD + tid] = s * inv;

#pragma unroll
    for (int i = 0; i < 2; ++i) {
        int t = tid + i * 512;
        if (t < Tn) {
            bool msk = mask[b * Tn + t] != 0;
            float e = energ[b * Tn + t];
            wout[b * Tn + t] = msk ? 0.f : __expf(e - M) * inv;
        }
    }
}

// ---------------------------------------------------------------------------
extern "C" void kernel_launch(void* const* d_in, const int* in_sizes, int n_in,
                              void* d_out, int out_size, void* d_ws, size_t ws_size,
                              hipStream_t stream) {
    const float* query  = (const float*)d_in[0];
    const float* memory = (const float*)d_in[1];
    const float* awc    = (const float*)d_in[2];
    const unsigned char* mask = (const unsigned char*)d_in[3];
    const float* Wq     = (const float*)d_in[4];
    const float* bq     = (const float*)d_in[5];
    const float* Wm     = (const float*)d_in[6];
    const float* bm     = (const float*)d_in[7];
    const float* Wv     = (const float*)d_in[8];
    const float* bv     = (const float*)d_in[9];
    const float* conv_w = (const float*)d_in[10];
    const float* conv_b = (const float*)d_in[11];
    const float* Wloc   = (const float*)d_in[12];

    float* out = (float*)d_out;
    float* ctx = out;             // [64,512]
    float* wout = out + Bsz * MD; // [64,1000]

    float* qsum  = (float*)d_ws;
    float* energ = (float*)((char*)d_ws + OFF_ENERG);
    short* WmF   = (short*)((char*)d_ws + OFF_WMF);
    short* W2F   = (short*)((char*)d_ws + OFF_W2F);
    float2* ml   = (float2*)((char*)d_ws + OFF_ML);
    float* ctxc  = (float*)((char*)d_ws + OFF_CTXC);
    short* memB  = (short*)((char*)d_ws + OFF_MEMB);

    k_prep<<<dim3(97), dim3(256), 0, stream>>>(Wm, conv_w, conv_b, Wloc, query, Wq,
                                               bq, bm, WmF, W2F, qsum);
    k_convert<<<dim3(2048), dim3(256), 0, stream>>>(memory, memB);
    k_fused<<<dim3(NCH, Bsz), dim3(512), 0, stream>>>(
        memB, awc, mask, WmF, W2F, Wv, bv, qsum, energ, ctxc, ml);
    k_combine<<<dim3(Bsz), dim3(512), 0, stream>>>(ctxc, ml, energ, mask, ctx, wout);
}